// Round 9
// baseline (751.116 us; speedup 1.0000x reference)
//
#include <hip/hip_runtime.h>
#include <math.h>

// Problem constants
#define FL 41            // filter length
#define NH 32            // hidden channels
// ws float offsets
#define WS_E0  0         // encode filter region0 [32][41]
#define WS_E1  1312
#define WS_G0  2624      // decode filter region0
#define WS_G1  3936
#define WS_W2T 5248      // normalized W2^T [32][256]
#define WS_Z   16384     // z intermediate [T1][32] (33.5 MB; ws >= 1.3 GB per fill evidence)

// ---------------------------------------------------------------- setup ----
__global__ __launch_bounds__(256) void setup_kernel(
    const float* __restrict__ V2, const float* __restrict__ mus,
    const float* __restrict__ sigmas, const float* __restrict__ scaling,
    float* __restrict__ ws)
{
    const int tid = threadIdx.x;
    __shared__ float nrm[NH];
    {
        const int h = tid >> 3;          // 0..31
        const int s = tid & 7;           // 0..7
        float p = 0.f;
        for (int jj = 0; jj < 32; ++jj) {
            const float v = V2[(s + jj*8)*NH + h];
            p += v*v;
        }
        p += __shfl_xor(p, 1, 8);
        p += __shfl_xor(p, 2, 8);
        p += __shfl_xor(p, 4, 8);
        if (s == 0) nrm[h] = sqrtf(p);
    }
    __syncthreads();
    for (int idx = tid; idx < NH*256; idx += 256) {
        int h = idx >> 8, j = idx & 255;
        ws[WS_W2T + idx] = V2[j*NH + h] / nrm[h];
    }
    for (int idx = tid; idx < 4*NH*FL; idx += 256) {
        int bank = idx / (NH*FL);
        int rem  = idx - bank*(NH*FL);
        int h = rem / FL, l = rem - h*FL;
        int r = bank & 1;
        float mu = mus[r*NH + h];
        float sg = fmaxf(sigmas[r*NH + h], 1.0f);  // clamp(min=1)
        float C  = scaling[r*NH + h];
        float m  = (bank < 2) ? -mu : mu;          // encode uses flipped mu
        float x  = (float)(l - 21);                // XVALS = -21..19
        float dd = (x - m) / sg;
        ws[idx] = C * expf(-0.5f * dd * dd);
    }
}

// -------------------------------------------------------------- projenc ----
// Fused proj + encode. Block: 512 thr, 128 x-rows -> 88 z-rows.
//   proj: z0/z1 rows [t0, t0+128) into LDS s[2][128][33] (never HBM).
//   encode: z[t,h] = sum_l s0[t+l][h]*e0[h,l] + s1[t+l][h]*e1[h,l] + b1[h]
// LDS: xT 33.8K + wT 9.2K + s 33.8K = 76.8 KB -> 2 blocks/CU.
#define PE_XR 128
#define PE_ZB 88
__global__ __launch_bounds__(512) void projenc_kernel(
    const float* __restrict__ x0, const float* __restrict__ x1,
    const float* __restrict__ W1, const float* __restrict__ b1,
    const float* __restrict__ ws, float* __restrict__ z,
    int T, int T1)
{
    __shared__ float xT[2][32][132];   // [region][c-in-chunk][row]
    __shared__ float wT[2][32][36];    // [region][c-in-chunk][h]
    __shared__ float s[2][PE_XR][33];  // z0/z1 tile, pad 33 (encode reads conflict-free)
    const int tid = threadIdx.x;
    const int t0  = blockIdx.x * PE_ZB;

    // proj thread mapping: rows 2m..2m+1, h0..h0+7, region rr
    const int m  = tid & 63;
    const int hq = (tid >> 6) & 3;
    const int h0 = hq * 8;
    const int rr = tid >> 8;

    float acc[2][8];
#pragma unroll
    for (int i = 0; i < 2; ++i)
#pragma unroll
        for (int j = 0; j < 8; ++j) acc[i][j] = 0.f;

    for (int kc = 0; kc < 4; ++kc) {
        const int c0 = kc * 32;
        // stage x chunk: 2 regions x 32 cols x 128 rows
#pragma unroll
        for (int r = 0; r < 2; ++r) {
            const float* __restrict__ xp = r ? x1 : x0;
#pragma unroll
            for (int p = 0; p < 2; ++p) {
                const int row = p*64 + (tid >> 3);
                const int c   = (tid & 7) * 4;
                const int gr  = t0 + row;
                float4 v = make_float4(0.f, 0.f, 0.f, 0.f);
                if (gr < T)
                    v = *reinterpret_cast<const float4*>(
                        &xp[(size_t)gr*128 + c0 + c]);
                xT[r][c+0][row] = v.x; xT[r][c+1][row] = v.y;
                xT[r][c+2][row] = v.z; xT[r][c+3][row] = v.w;
            }
        }
        // stage W chunk: 512 thr cover 2 regions x 32 h x 32 cols
        {
            const int h  = (tid >> 3) & 31;
            const int wr = tid >> 8;
            const int c  = (tid & 7) * 4;
            const float4 a = *reinterpret_cast<const float4*>(
                &W1[h*256 + wr*128 + c0 + c]);
            wT[wr][c+0][h] = a.x; wT[wr][c+1][h] = a.y;
            wT[wr][c+2][h] = a.z; wT[wr][c+3][h] = a.w;
        }
        __syncthreads();
#pragma unroll
        for (int c = 0; c < 32; ++c) {
            const float2 xv = *reinterpret_cast<const float2*>(&xT[rr][c][2*m]);
            const float4 wa = *reinterpret_cast<const float4*>(&wT[rr][c][h0]);
            const float4 wb = *reinterpret_cast<const float4*>(&wT[rr][c][h0+4]);
            const float wv[8] = {wa.x, wa.y, wa.z, wa.w, wb.x, wb.y, wb.z, wb.w};
#pragma unroll
            for (int j = 0; j < 8; ++j) {
                acc[0][j] += xv.x * wv[j];
                acc[1][j] += xv.y * wv[j];
            }
        }
        __syncthreads();
    }
    // acc -> s tile
#pragma unroll
    for (int i = 0; i < 2; ++i)
#pragma unroll
        for (int j = 0; j < 8; ++j) s[rr][2*m + i][h0 + j] = acc[i][j];
    __syncthreads();

    // ---- encode phase: 16 grps x 6 z-rows (88 valid, guard)
    {
        const int h   = tid & 31;
        const int grp = tid >> 5;      // 0..15
        const int tb  = grp * 6;
        float fa[6];
        const float bb = b1[h];
#pragma unroll
        for (int i = 0; i < 6; ++i) fa[i] = bb;
        float fr[FL];
#pragma unroll
        for (int l = 0; l < FL; ++l) fr[l] = ws[WS_E0 + h*FL + l];
#pragma unroll
        for (int ss = 0; ss < 46; ++ss) {
            const int srow = tb + ss;
            const float a0 = (srow < PE_XR) ? s[0][srow][h] : 0.f;
#pragma unroll
            for (int i = 0; i < 6; ++i) {
                const int l = ss - i;
                if (l >= 0 && l < FL) fa[i] += a0 * fr[l];
            }
        }
#pragma unroll
        for (int l = 0; l < FL; ++l) fr[l] = ws[WS_E1 + h*FL + l];
#pragma unroll
        for (int ss = 0; ss < 46; ++ss) {
            const int srow = tb + ss;
            const float a1 = (srow < PE_XR) ? s[1][srow][h] : 0.f;
#pragma unroll
            for (int i = 0; i < 6; ++i) {
                const int l = ss - i;
                if (l >= 0 && l < FL) fa[i] += a1 * fr[l];
            }
        }
#pragma unroll
        for (int i = 0; i < 6; ++i) {
            const int t = t0 + tb + i;
            if ((tb + i) < PE_ZB && t < T1) z[(size_t)t*NH + h] = fa[i];
        }
    }
}

// -------------------------------------------------------------- decread ----
// Fused decode + readout. Block: 512 thr, 64 zd-rows.
//   decode: zd_r[t,h] = sum_l z[t+l,h]*g_r[h,l]  (writes HBM + zd_lds)
//   readout: xh_r[t,j] = sum_h zd_r[t,h]*W2T[h][r*128+j] + b2[r*128+j]
// LDS: sz 13.3K + w2 33.8K + zd_lds 16.4K = 63.5 KB -> 2 blocks/CU.
#define DR_BT 64
#define DR_RS 104   // staged z rows (64 + 40)
__global__ __launch_bounds__(512) void decread_kernel(
    const float* __restrict__ z, const float* __restrict__ ws,
    const float* __restrict__ W2T, const float* __restrict__ b2,
    float* __restrict__ zd0, float* __restrict__ zd1,
    float* __restrict__ xh0, float* __restrict__ xh1,
    int T1, int T2)
{
    __shared__ float sz[DR_RS][NH];
    __shared__ float w2[2][NH][132];
    __shared__ float zdl[2][DR_BT][NH];
    const int tid = threadIdx.x;
    const int t0  = blockIdx.x * DR_BT;

    // stage z rows [t0, t0+104)
    for (int idx = tid; idx < DR_RS*NH/4; idx += 512) {
        const int row = idx >> 3, col = (idx & 7) * 4;
        const int t   = t0 + row;
        float4 v = make_float4(0.f, 0.f, 0.f, 0.f);
        if (t < T1)
            v = *reinterpret_cast<const float4*>(&z[(size_t)t*NH + col]);
        *reinterpret_cast<float4*>(&sz[row][col]) = v;
    }
    // stage W2T (L2-hot): 2048 float4s
    for (int idx = tid; idx < 2048; idx += 512) {
        const int h  = idx >> 6;
        const int jj = (idx & 63) * 4;
        const int r  = jj >> 7;
        const int j  = jj & 127;
        *reinterpret_cast<float4*>(&w2[r][h][j]) =
            *reinterpret_cast<const float4*>(&W2T[h*256 + jj]);
    }
    __syncthreads();

    // ---- decode: h = tid&31, region = bit5, 8 grps x 8 rows
    {
        const int h   = tid & 31;
        const int rr  = (tid >> 5) & 1;
        const int grp = tid >> 6;      // 0..7
        const int tb  = grp * 8;
        float fr[FL];
        const float* __restrict__ fb = ws + (rr ? WS_G1 : WS_G0);
#pragma unroll
        for (int l = 0; l < FL; ++l) fr[l] = fb[h*FL + l];
        float acc[8];
#pragma unroll
        for (int i = 0; i < 8; ++i) acc[i] = 0.f;
#pragma unroll
        for (int ss = 0; ss < 48; ++ss) {
            const float a = sz[tb + ss][h];
#pragma unroll
            for (int i = 0; i < 8; ++i) {
                const int l = ss - i;
                if (l >= 0 && l < FL) acc[i] += a * fr[l];
            }
        }
        float* __restrict__ zd = rr ? zd1 : zd0;
#pragma unroll
        for (int i = 0; i < 8; ++i) {
            zdl[rr][tb + i][h] = acc[i];
            const int t = t0 + tb + i;
            if (t < T2) zd[(size_t)t*NH + h] = acc[i];
        }
    }
    __syncthreads();

    // ---- readout: j = (tid&31)*4 contiguous, region = bit5, 8 grps x 8 rows
    {
        const int jl  = (tid & 31) * 4;
        const int r   = (tid >> 5) & 1;
        const int rw  = tid >> 6;      // 0..7
        const int tb  = rw * 8;
        float acc[8][4];
        {
            const float4 bv = *reinterpret_cast<const float4*>(&b2[r*128 + jl]);
#pragma unroll
            for (int i = 0; i < 8; ++i) {
                acc[i][0] = bv.x; acc[i][1] = bv.y;
                acc[i][2] = bv.z; acc[i][3] = bv.w;
            }
        }
#pragma unroll 4
        for (int h = 0; h < NH; ++h) {
            const float4 w = *reinterpret_cast<const float4*>(&w2[r][h][jl]);
#pragma unroll
            for (int i = 0; i < 8; ++i) {
                const float zv = zdl[r][tb + i][h];
                acc[i][0] += zv * w.x;
                acc[i][1] += zv * w.y;
                acc[i][2] += zv * w.z;
                acc[i][3] += zv * w.w;
            }
        }
        float* __restrict__ xp = r ? xh1 : xh0;
#pragma unroll
        for (int i = 0; i < 8; ++i) {
            const int t = t0 + tb + i;
            if (t < T2) {
                float4 o = make_float4(acc[i][0], acc[i][1], acc[i][2], acc[i][3]);
                *reinterpret_cast<float4*>(&xp[(size_t)t*128 + jl]) = o;
            }
        }
    }
}

// ---------------------------------------------------------------- launch ---
extern "C" void kernel_launch(void* const* d_in, const int* in_sizes, int n_in,
                              void* d_out, int out_size, void* d_ws, size_t ws_size,
                              hipStream_t stream)
{
    const float* x0      = (const float*)d_in[0];
    const float* x1      = (const float*)d_in[1];
    const float* W1      = (const float*)d_in[2];
    const float* b1      = (const float*)d_in[3];
    const float* V2      = (const float*)d_in[4];
    const float* b2      = (const float*)d_in[5];
    const float* mus     = (const float*)d_in[6];
    const float* sigmas  = (const float*)d_in[7];
    const float* scaling = (const float*)d_in[8];
    float* out = (float*)d_out;
    float* ws  = (float*)d_ws;

    const int T  = in_sizes[0] / 128;
    const int T1 = T - 40;
    const int T2 = T - 80;

    float* zd0 = out;
    float* zd1 = out + (size_t)T2 * NH;
    float* xh0 = out + (size_t)2 * T2 * NH;
    float* xh1 = xh0 + (size_t)T2 * 128;
    float* z   = ws + WS_Z;   // 33.5 MB in d_ws (>= 1.3 GB per fill evidence)

    setup_kernel<<<1, 256, 0, stream>>>(V2, mus, sigmas, scaling, ws);
    projenc_kernel<<<(T1 + PE_ZB - 1) / PE_ZB, 512, 0, stream>>>(
        x0, x1, W1, b1, ws, z, T, T1);
    decread_kernel<<<(T2 + DR_BT - 1) / DR_BT, 512, 0, stream>>>(
        z, ws, ws + WS_W2T, b2, zd0, zd1, xh0, xh1, T1, T2);
}